// Round 7
// baseline (710.346 us; speedup 1.0000x reference)
//
#include <hip/hip_runtime.h>
#include <hip/hip_bf16.h>
#include <stdint.h>

// Problem constants
#define BATCH 16
#define SEQ   1024
#define HIDN  1024
#define NH    16
#define HD    64
#define PBSTRIDE 1025  // pos_bias last-dim stride (2*512+1)

// LDS strides chosen so stride ≡ 6 (mod 32) dwords -> bank = 6*fr+4*g, <=2-way (free)
#define KST 76    // K tile stride (shorts): 152B = 38dw = 6 mod 32
#define VST 140   // V^T / P tile stride (shorts): 280B = 70dw = 6 mod 32

typedef __attribute__((ext_vector_type(8))) short short8;
typedef __attribute__((ext_vector_type(4))) short short4v;
typedef __attribute__((ext_vector_type(4))) float f32x4;

__device__ __forceinline__ float bf2f(short x) {
    unsigned int u = ((unsigned int)(unsigned short)x) << 16;
    union { unsigned int u; float f; } c; c.u = u; return c.f;
}
__device__ __forceinline__ short f2bf(float f) {
    union { float f; unsigned int u; } c; c.f = f;
    unsigned int r = c.u + 0x7FFFu + ((c.u >> 16) & 1u);  // RNE
    return (short)(r >> 16);
}

typedef __attribute__((address_space(1))) void gvoid;
typedef __attribute__((address_space(3))) void svoid;
__device__ __forceinline__ void gload_lds16(const void* g, void* l) {
    __builtin_amdgcn_global_load_lds((gvoid*)g, (svoid*)l, 16, 0, 0);
}

// -------- weight conversion fp32 -> bf16 --------
__global__ void convw_k(const float* __restrict__ src, short* __restrict__ dst) {
    int i = (blockIdx.x * 256 + threadIdx.x) * 4;
    float4 f = *(const float4*)(src + i);
    short4v o;
    o[0] = f2bf(f.x); o[1] = f2bf(f.y); o[2] = f2bf(f.z); o[3] = f2bf(f.w);
    *(short4v*)(dst + i) = o;
}

// -------- fuse q/k/v biases into one contiguous fp32 [3072] --------
__global__ void convb_k(const float* __restrict__ b0, const float* __restrict__ b1,
                        const float* __restrict__ b2, float* __restrict__ fb) {
    int i = blockIdx.x * 256 + threadIdx.x;  // 0..3071
    const float* s = (i < 1024) ? b0 : (i < 2048) ? b1 : b2;
    fb[i] = s[i & 1023];
}

// -------- posemb: hs_bf16 = fp32(hidden) + pos * W_pe + b_pe --------
__global__ void posemb_k(const float* __restrict__ hid, const float* __restrict__ wpe,
                         const float* __restrict__ bpe, short* __restrict__ hs) {
    long long idx = (long long)blockIdx.x * blockDim.x + threadIdx.x;
    long long base = idx * 8;
    int c = (int)(base & (HIDN - 1));
    int s = (int)((base >> 10) & (SEQ - 1));
    float pos = (float)(s - 512) * (1.0f / 512.0f);
    float4 h0 = *(const float4*)(hid + base);
    float4 h1 = *(const float4*)(hid + base + 4);
    float4 w0 = *(const float4*)(wpe + c);
    float4 w1 = *(const float4*)(wpe + c + 4);
    float4 b0 = *(const float4*)(bpe + c);
    float4 b1 = *(const float4*)(bpe + c + 4);
    short8 ov;
    ov[0] = f2bf(h0.x + pos * w0.x + b0.x);
    ov[1] = f2bf(h0.y + pos * w0.y + b0.y);
    ov[2] = f2bf(h0.z + pos * w0.z + b0.z);
    ov[3] = f2bf(h0.w + pos * w0.w + b0.w);
    ov[4] = f2bf(h1.x + pos * w1.x + b1.x);
    ov[5] = f2bf(h1.y + pos * w1.y + b1.y);
    ov[6] = f2bf(h1.z + pos * w1.z + b1.z);
    ov[7] = f2bf(h1.w + pos * w1.w + b1.w);
    *(short8*)(hs + base) = ov;
}

// -------- fused QKV GEMM: [16384,1024] @ [3072,1024]^T + fb --------
// grid (24,128). which = tn>>10 (block-uniform): 0->q [B,H,S,D], 1->k [B,H,S,D], 2->v^T [B,H,D,S]
__global__ __launch_bounds__(256) void gemm_qkv(const short* __restrict__ A,
                                                const short* __restrict__ W,
                                                const float* __restrict__ fb,
                                                short* __restrict__ q,
                                                short* __restrict__ k,
                                                short* __restrict__ vt) {
    __shared__ __align__(16) short Als[128 * 32];
    __shared__ __align__(16) short Bls[128 * 32];
    const int tid  = threadIdx.x;
    const int lane = tid & 63;
    const int w    = tid >> 6;
    const int wr   = w >> 1, wc = w & 1;
    const int tm   = blockIdx.y * 128;
    const int tn   = blockIdx.x * 128;

    f32x4 acc[4][4] = {};

    const int srow = tid >> 2;
    const int skb  = (tid & 3) * 8;
    const long long a_base = (long long)(tm + srow) * 1024 + skb;
    const long long b_base = (long long)(tn + srow) * 1024 + skb;
    const int ldsw = w * 1024;

    const int fr = lane & 15;
    const int fg = (lane >> 4) * 8;

    for (int k0 = 0; k0 < 1024; k0 += 32) {
#pragma unroll
        for (int i = 0; i < 2; ++i) {
            gload_lds16((const void*)(A + a_base + (long long)i * 64 * 1024 + k0),
                        (void*)((char*)Als + i * 4096 + ldsw));
            gload_lds16((const void*)(W + b_base + (long long)i * 64 * 1024 + k0),
                        (void*)((char*)Bls + i * 4096 + ldsw));
        }
        __syncthreads();
        short8 af[4], bfr[4];
#pragma unroll
        for (int r = 0; r < 4; ++r) {
            af[r]  = *(const short8*)(Als + (wr * 64 + r * 16 + fr) * 32 + fg);
            bfr[r] = *(const short8*)(Bls + (wc * 64 + r * 16 + fr) * 32 + fg);
        }
#pragma unroll
        for (int mi = 0; mi < 4; ++mi)
#pragma unroll
            for (int ni = 0; ni < 4; ++ni)
                acc[mi][ni] = __builtin_amdgcn_mfma_f32_16x16x32_bf16(af[mi], bfr[ni], acc[mi][ni], 0, 0, 0);
        __syncthreads();
    }

    const int which = tn >> 10;  // block-uniform
    short* dst = (which == 0) ? q : (which == 1) ? k : vt;
    const int g4 = (lane >> 4) * 4;
#pragma unroll
    for (int ni = 0; ni < 4; ++ni) {
        int col = tn + wc * 64 + ni * 16 + fr;
        int cc  = col & 1023;
        int h   = cc >> 6, d = cc & 63;
        float bv = fb[col];
#pragma unroll
        for (int mi = 0; mi < 4; ++mi) {
#pragma unroll
            for (int r = 0; r < 4; ++r) {
                int row = tm + wr * 64 + mi * 16 + g4 + r;
                int b = row >> 10, s = row & 1023;
                short o = f2bf(acc[mi][ni][r] + bv);
                if (which < 2)
                    dst[(((long long)(b * NH + h) * SEQ + s) << 6) + d] = o;
                else
                    dst[((long long)(b * NH + h) * HD + d) * SEQ + s] = o;
            }
        }
    }
}

// -------- out-proj GEMM: fp32 out --------
__global__ __launch_bounds__(256) void gemm_out(const short* __restrict__ A,
                                                const short* __restrict__ W,
                                                const float* __restrict__ bias,
                                                float* __restrict__ Cout) {
    __shared__ __align__(16) short Als[128 * 32];
    __shared__ __align__(16) short Bls[128 * 32];
    const int tid  = threadIdx.x;
    const int lane = tid & 63;
    const int w    = tid >> 6;
    const int wr   = w >> 1, wc = w & 1;
    const int tm   = blockIdx.y * 128;
    const int tn   = blockIdx.x * 128;

    f32x4 acc[4][4] = {};

    const int srow = tid >> 2;
    const int skb  = (tid & 3) * 8;
    const long long a_base = (long long)(tm + srow) * 1024 + skb;
    const long long b_base = (long long)(tn + srow) * 1024 + skb;
    const int ldsw = w * 1024;

    const int fr = lane & 15;
    const int fg = (lane >> 4) * 8;

    for (int k0 = 0; k0 < 1024; k0 += 32) {
#pragma unroll
        for (int i = 0; i < 2; ++i) {
            gload_lds16((const void*)(A + a_base + (long long)i * 64 * 1024 + k0),
                        (void*)((char*)Als + i * 4096 + ldsw));
            gload_lds16((const void*)(W + b_base + (long long)i * 64 * 1024 + k0),
                        (void*)((char*)Bls + i * 4096 + ldsw));
        }
        __syncthreads();
        short8 af[4], bfr[4];
#pragma unroll
        for (int r = 0; r < 4; ++r) {
            af[r]  = *(const short8*)(Als + (wr * 64 + r * 16 + fr) * 32 + fg);
            bfr[r] = *(const short8*)(Bls + (wc * 64 + r * 16 + fr) * 32 + fg);
        }
#pragma unroll
        for (int mi = 0; mi < 4; ++mi)
#pragma unroll
            for (int ni = 0; ni < 4; ++ni)
                acc[mi][ni] = __builtin_amdgcn_mfma_f32_16x16x32_bf16(af[mi], bfr[ni], acc[mi][ni], 0, 0, 0);
        __syncthreads();
    }

    const int g4 = (lane >> 4) * 4;
#pragma unroll
    for (int ni = 0; ni < 4; ++ni) {
        int col = tn + wc * 64 + ni * 16 + fr;
        float bv = bias[col];
#pragma unroll
        for (int mi = 0; mi < 4; ++mi)
#pragma unroll
            for (int r = 0; r < 4; ++r) {
                int row = tm + wr * 64 + mi * 16 + g4 + r;
                Cout[(long long)row * 1024 + col] = acc[mi][ni][r] + bv;
            }
    }
}

// -------- attention v4: round-4 structure + V^T global layout + bank-clean strides --------
// grid: x = q-tile (8), y = b*h (256). 256 threads = 4 waves, wave owns 32 q-rows.
__global__ __launch_bounds__(256) void attn_k(const short* __restrict__ Q,
                                              const short* __restrict__ Kg,
                                              const short* __restrict__ Vt,
                                              const float* __restrict__ pbias,
                                              short* __restrict__ ctx) {
    __shared__ __align__(16) short Kls[128 * KST];      // K tile [key][d]
    __shared__ __align__(16) short Vls[64 * VST];       // V^T tile [d][key]
    __shared__ __align__(16) short Pls[4 * 32 * VST];   // per-wave P [qrow][key]
    __shared__ __align__(16) float pbl[SEQ];            // pos_bias head slice

    const int tid  = threadIdx.x;
    const int lane = tid & 63;
    const int w    = tid >> 6;
    const int bh   = blockIdx.y;
    const int h    = bh & (NH - 1);
    const int qt   = blockIdx.x;
    const long long base = (long long)bh * (SEQ * HD);

    const int fr = lane & 15;
    const int fg = lane >> 4;

    {   // stage pos_bias head slice (barriers inside kt loop precede first use)
        const float* pbh = pbias + h * PBSTRIDE;
        for (int i = tid; i < SEQ; i += 256) pbl[i] = pbh[i];
    }

    // Q fragments (A-operand): rows qt*128 + w*32 + mi*16 + fr, d = ks*32 + fg*8; 0.125 folded (exact)
    short8 qf[2][2];
#pragma unroll
    for (int mi = 0; mi < 2; ++mi)
#pragma unroll
        for (int ks = 0; ks < 2; ++ks) {
            short8 t = *(const short8*)(Q + base + (long long)(qt * 128 + w * 32 + mi * 16 + fr) * HD + ks * 32 + fg * 8);
#pragma unroll
            for (int j = 0; j < 8; ++j) t[j] = f2bf(bf2f(t[j]) * 0.125f);
            qf[mi][ks] = t;
        }

    f32x4 o[2][4] = {};
    float mrun[2][4], lrun[2][4];
#pragma unroll
    for (int mi = 0; mi < 2; ++mi)
#pragma unroll
        for (int r = 0; r < 4; ++r) { mrun[mi][r] = -1e30f; lrun[mi][r] = 0.0f; }

    short* Pw = Pls + w * 32 * VST;

    const int rrow = tid >> 3;            // 0..31
    const int dcol = (tid & 7) * 8;       // K staging col
    const int vcol = (tid & 7) * 16;      // V^T staging col

    for (int kt = 0; kt < 8; ++kt) {
        __syncthreads();  // protect K/V LDS against previous iteration's reads
        {   // K tile [128][KST]: b128 loads/writes (1KB contiguous per wave-row-group)
#pragma unroll
            for (int i = 0; i < 4; ++i) {
                short8 kv = *(const short8*)(Kg + base + (long long)(kt * 128 + i * 32 + rrow) * HD + dcol);
                *(short8*)(Kls + (i * 32 + rrow) * KST + dcol) = kv;
            }
            // V^T tile [64][VST]: linear b128 writes from V^T global (no scatter)
#pragma unroll
            for (int i = 0; i < 2; ++i) {
                int d = i * 32 + rrow;
                const short* gsrc = Vt + base + (long long)d * SEQ + kt * 128 + vcol;
                short8 v0 = *(const short8*)(gsrc);
                short8 v1 = *(const short8*)(gsrc + 8);
                *(short8*)(Vls + d * VST + vcol)     = v0;
                *(short8*)(Vls + d * VST + vcol + 8) = v1;
            }
        }
        __syncthreads();

        // S = Q K^T (per wave 32x128)
        f32x4 sc[2][8] = {};
#pragma unroll
        for (int ks = 0; ks < 2; ++ks) {
#pragma unroll
            for (int ni = 0; ni < 8; ++ni) {
                short8 kb = *(const short8*)(Kls + (ni * 16 + fr) * KST + ks * 32 + fg * 8);
#pragma unroll
                for (int mi = 0; mi < 2; ++mi)
                    sc[mi][ni] = __builtin_amdgcn_mfma_f32_16x16x32_bf16(qf[mi][ks], kb, sc[mi][ni], 0, 0, 0);
            }
        }

        // + learned key bias (scale already folded into Q)
        float pb[8];
#pragma unroll
        for (int ni = 0; ni < 8; ++ni)
            pb[ni] = pbl[kt * 128 + ni * 16 + fr];
#pragma unroll
        for (int mi = 0; mi < 2; ++mi)
#pragma unroll
            for (int ni = 0; ni < 8; ++ni)
#pragma unroll
                for (int r = 0; r < 4; ++r)
                    sc[mi][ni][r] += pb[ni];

        // online softmax per row (row = w*32 + mi*16 + fg*4 + r, spread over 16 fr-lanes)
#pragma unroll
        for (int mi = 0; mi < 2; ++mi) {
#pragma unroll
            for (int r = 0; r < 4; ++r) {
                float tmax = sc[mi][0][r];
#pragma unroll
                for (int ni = 1; ni < 8; ++ni) tmax = fmaxf(tmax, sc[mi][ni][r]);
#pragma unroll
                for (int off = 1; off < 16; off <<= 1)
                    tmax = fmaxf(tmax, __shfl_xor(tmax, off));
                float mnew = fmaxf(mrun[mi][r], tmax);
                float scl  = __expf(mrun[mi][r] - mnew);
                mrun[mi][r] = mnew;
                lrun[mi][r] *= scl;
#pragma unroll
                for (int di = 0; di < 4; ++di) o[mi][di][r] *= scl;
                float psum = 0.0f;
#pragma unroll
                for (int ni = 0; ni < 8; ++ni) {
                    float p = __expf(sc[mi][ni][r] - mnew);
                    sc[mi][ni][r] = p;
                    psum += p;
                }
#pragma unroll
                for (int off = 1; off < 16; off <<= 1)
                    psum += __shfl_xor(psum, off);
                lrun[mi][r] += psum;
            }
        }

        // write P (bf16) to this wave's LDS region (stride 140: 32 distinct banks/instr)
#pragma unroll
        for (int mi = 0; mi < 2; ++mi)
#pragma unroll
            for (int ni = 0; ni < 8; ++ni)
#pragma unroll
                for (int r = 0; r < 4; ++r)
                    Pw[(mi * 16 + fg * 4 + r) * VST + ni * 16 + fr] = f2bf(sc[mi][ni][r]);

        // O += P V
#pragma unroll
        for (int ks = 0; ks < 4; ++ks) {
            short8 pa[2];
#pragma unroll
            for (int mi = 0; mi < 2; ++mi)
                pa[mi] = *(const short8*)(Pw + (mi * 16 + fr) * VST + ks * 32 + fg * 8);
#pragma unroll
            for (int di = 0; di < 4; ++di) {
                short8 vb = *(const short8*)(Vls + (di * 16 + fr) * VST + ks * 32 + fg * 8);
#pragma unroll
                for (int mi = 0; mi < 2; ++mi)
                    o[mi][di] = __builtin_amdgcn_mfma_f32_16x16x32_bf16(pa[mi], vb, o[mi][di], 0, 0, 0);
            }
        }
    }

    // normalize + store ctx as [B, S, HID]
    const int b = bh >> 4;
#pragma unroll
    for (int mi = 0; mi < 2; ++mi) {
#pragma unroll
        for (int r = 0; r < 4; ++r) {
            float inv = 1.0f / lrun[mi][r];
            int srow = qt * 128 + w * 32 + mi * 16 + fg * 4 + r;
#pragma unroll
            for (int di = 0; di < 4; ++di) {
                int d = di * 16 + fr;
                ctx[(long long)(b * SEQ + srow) * HIDN + h * HD + d] = f2bf(o[mi][di][r] * inv);
            }
        }
    }
}

// ---------------- launcher ----------------
extern "C" void kernel_launch(void* const* d_in, const int* in_sizes, int n_in,
                              void* d_out, int out_size, void* d_ws, size_t ws_size,
                              hipStream_t stream) {
    const float* hid  = (const float*)d_in[0];
    const float* Wq   = (const float*)d_in[1];
    const float* bq   = (const float*)d_in[2];
    const float* Wk   = (const float*)d_in[3];
    const float* bk   = (const float*)d_in[4];
    const float* Wv   = (const float*)d_in[5];
    const float* bv   = (const float*)d_in[6];
    const float* Wo   = (const float*)d_in[7];
    const float* bo   = (const float*)d_in[8];
    const float* Wpe  = (const float*)d_in[9];
    const float* bpe  = (const float*)d_in[10];
    const float* pbias = (const float*)d_in[11];

    const long long NE = (long long)BATCH * SEQ * HIDN;  // 16M elements
    const long long WSZ = (long long)HIDN * HIDN;        // 1M elements per weight

    // ws (shorts): hs | v^T | Wcq|Wck|Wcv (contiguous fused [3072][1024]) | Wco | fbias(fp32)
    short* hs   = (short*)d_ws;
    short* vt   = hs + NE;
    short* Wcq  = vt + NE;
    short* Wck  = Wcq + WSZ;
    short* Wcv  = Wck + WSZ;
    short* Wco  = Wcv + WSZ;
    float* fb   = (float*)(Wco + WSZ);
    // d_out: q [0,NE) shorts | k [NE,2NE) shorts — dead before final GEMM overwrites
    short* q    = (short*)d_out;
    short* k    = q + NE;
    short* ctx  = hs;  // alias: hs dead after QKV projection

    posemb_k<<<(int)(NE / 8 / 256), 256, 0, stream>>>(hid, Wpe, bpe, hs);
    convw_k<<<(int)(WSZ / 4 / 256), 256, 0, stream>>>(Wq, Wcq);
    convw_k<<<(int)(WSZ / 4 / 256), 256, 0, stream>>>(Wk, Wck);
    convw_k<<<(int)(WSZ / 4 / 256), 256, 0, stream>>>(Wv, Wcv);
    convw_k<<<(int)(WSZ / 4 / 256), 256, 0, stream>>>(Wo, Wco);
    convb_k<<<12, 256, 0, stream>>>(bq, bk, bv, fb);

    gemm_qkv<<<dim3(24, 128), 256, 0, stream>>>(hs, Wcq, fb, q, k, vt);

    attn_k<<<dim3(8, 256), 256, 0, stream>>>(q, k, vt, pbias, ctx);

    gemm_out<<<dim3(8, 128), 256, 0, stream>>>(ctx, Wco, bo, (float*)d_out);
}